// Round 12
// baseline (372.854 us; speedup 1.0000x reference)
//
#include <hip/hip_runtime.h>
#include <math.h>

// ConvKAN3D: 3x [conv3d(3x3x3,pad1) -> cubic KAN spline + SiLU -> BN(eval) -> maxpool 2x2x2]
// then global mean pool + fc1/relu/fc2.
// Fused per layer. Width-16 global_load_lds staging (4-dword-aligned chunk grid,
// invalid chunks DMA from a zero scratch buffer). CSPLIT: block = CSPLIT cin-groups
// x SP spatial threads; each group reduces its cin range into private acc, groups
// combine via one LDS reduction. r11: CSPLIT=4 on L3 gave ~2x (latency-bound at low
// wave count); r12 applies the same shape to L2 (chain 32->8, 4x DMA streams).
// HARD CONSTRAINTS (measured): G<=4 with r[64] (G=8 spills: r8 WRITE 964MB);
// launch_bounds must stay (TPB,2) (r6: bounds 3 -> VGPR 84 + spill);
// never split cin via global atomics (r5: 1.86GB HBM traffic).

#define GLOBAL_AS __attribute__((address_space(1)))
#define LDS_AS    __attribute__((address_space(3)))

static __device__ __forceinline__ void async_ld16(const float* g, float* l) {
    __builtin_amdgcn_global_load_lds((const GLOBAL_AS void*)g, (LDS_AS void*)l,
                                     16, 0, 0);
}

template <int TPB_, int CIN, int CSPLIT, int G, int PDT, int PHT, int PWT>
__global__ __launch_bounds__(TPB_, 2) void spline_block_kernel(
    const float* __restrict__ x,    // [N, CIN, D, H, W]
    const float* __restrict__ cw,   // [Cout, CIN, 27]
    const float* __restrict__ cb,   // [Cout]
    const float* __restrict__ knots,// [10]
    const float* __restrict__ sw,   // [Cout, 10]
    const float* __restrict__ w1,
    const float* __restrict__ w2,
    const float* __restrict__ g,
    const float* __restrict__ beta,
    const float* __restrict__ zbuf, // >=64B of zeros (16B aligned)
    float* __restrict__ out,        // [N, Cout, D/2, H/2, W/2]
    int N, int Cout, int D, int H, int W,
    int ntiles, int nthw, int ntw)
{
    constexpr int SP     = PDT * PHT * PWT;    // spatial threads per group
    constexpr int CPG    = CIN / CSPLIT;       // cins per group
    constexpr int ID     = 2 * PDT + 2;
    constexpr int IH     = 2 * PHT + 2;
    constexpr int PITCH  = 24;                 // 6 chunks of 4 dwords
    constexpr int ROWS   = ID * IH;
    constexpr int CHUNKS = ROWS * 6;
    constexpr int PHYS   = ROWS * PITCH;       // dwords == CHUNKS*4
    constexpr int NCH    = (CHUNKS + SP - 1) / SP;
    constexpr int BUFS   = (CPG > 1) ? 2 : 1;
    static_assert(SP * CSPLIT == TPB_, "block = CSPLIT x SP");
    static_assert(CIN % CSPLIT == 0, "cin divisible");
    static_assert(NCH <= 32, "mask fits u32");
    static_assert(CSPLIT == 1 ||
                  (CSPLIT - 1) * SP * G * 8 <= CSPLIT * BUFS * PHYS,
                  "reduction scratch fits in tile");

    __shared__ __align__(16) float tile[CSPLIT][BUFS][PHYS];
    __shared__ float  wlds[CIN * G * 28];
    __shared__ float4 stbl[G * 11];            // spline prefix coeffs {A,3B,3C,D}

    const int PD = D >> 1, PH = H >> 1, PW = W >> 1;
    const int groups = Cout / G;
    const int tid  = threadIdx.x;
    const int cg   = tid / SP;                 // cin-group id
    const int stid = tid % SP;                 // spatial thread id

    const int bx      = blockIdx.x;
    const int tile_id = bx % ntiles;
    const int t1      = bx / ntiles;
    const int grp     = t1 % groups;
    const int n       = t1 / groups;
    const int c0      = grp * G;
    const int cinbase = cg * CPG;

    const int td  = tile_id / nthw;
    const int rem = tile_id % nthw;
    const int th_ = rem / ntw;
    const int tw_ = rem % ntw;

    // stage weights + spline table (covered by first barrier)
    for (int i = tid; i < CIN * G * 27; i += TPB_) {
        const int t  = i % 27;
        const int cgr = i / 27;
        const int gg = cgr % G;
        const int ci = cgr / G;
        wlds[cgr * 28 + t] = cw[((c0 + gg) * CIN + ci) * 27 + t];
    }
    for (int i = tid; i < G * 11; i += TPB_) {
        const int gg  = i / 11;
        const int cnt = i % 11;
        const int c   = c0 + gg;
        float A = 0.f, B3 = 0.f, C3 = 0.f, Dd = 0.f;
        for (int j = 0; j < cnt; j++) {
            const float s = sw[c * 10 + j];
            const float k = knots[j];
            A  += s;
            B3 += 3.0f * s * k;
            C3 += 3.0f * s * k * k;
            Dd += s * k * k * k;
        }
        stbl[i] = make_float4(A, B3, C3, Dd);
    }

    const int pwl = stid % PWT;
    const int phl = (stid / PWT) % PHT;
    const int pdl = stid / (PWT * PHT);

    const int pd0 = td * PDT, ph0 = th_ * PHT, pw0 = tw_ * PWT;
    const int d0 = 2 * pd0 - 1, h0 = 2 * ph0 - 1;
    const int w0 = 2 * pw0 - 1;
    const int wb = w0 & ~3;                    // 4-dword aligned chunk origin
    const int woff = w0 - wb;                  // 1 or 3

    // per-chunk global offsets + validity (same for all cins; spatial-tile based)
    int off[NCH];
    unsigned vm = 0;
#pragma unroll
    for (int k = 0; k < NCH; k++) {
        const int chunk = stid + SP * k;
        const int row = chunk / 6, cs = chunk - row * 6;
        const int dz = row / IH, hy = row - dz * IH;
        const int dd = d0 + dz, hh = h0 + hy;
        const int wsd = wb + cs * 4;
        const bool ok = (chunk < CHUNKS) &
                        ((unsigned)dd < (unsigned)D) &
                        ((unsigned)hh < (unsigned)H) &
                        ((unsigned)wsd < (unsigned)W);
        off[k] = ok ? (dd * H + hh) * W + wsd : 0;
        vm |= (unsigned)ok << k;
    }

    const size_t chstride = (size_t)D * H * W;
    const float* xn = x + (size_t)n * CIN * chstride;

    float acc[G][8];
#pragma unroll
    for (int gg = 0; gg < G; gg++)
#pragma unroll
        for (int i = 0; i < 8; i++) acc[gg][i] = 0.0f;

    __syncthreads();   // weights/table visible before first reads

    // each group stages its first cin into its buf 0
    {
        const float* xc = xn + (size_t)cinbase * chstride;
        float* dst = &tile[cg][0][0];
#pragma unroll
        for (int k = 0; k < NCH; k++) {
            const int chunk = stid + SP * k;
            if ((k + 1) * SP <= CHUNKS || chunk < CHUNKS) {
                const float* src = ((vm >> k) & 1) ? (xc + off[k]) : zbuf;
                async_ld16(src, dst + chunk * 4);
            }
        }
    }
    __syncthreads();

    int cur = 0;
#pragma unroll 1
    for (int s = 0; s < CPG; s++) {
        // prefetch this group's next cin into its other buffer
        if (s + 1 < CPG) {
            const float* xc = xn + (size_t)(cinbase + s + 1) * chstride;
            float* dst = &tile[cg][cur ^ (BUFS - 1)][0];
#pragma unroll
            for (int k = 0; k < NCH; k++) {
                const int chunk = stid + SP * k;
                if ((k + 1) * SP <= CHUNKS || chunk < CHUNKS) {
                    const float* src = ((vm >> k) & 1) ? (xc + off[k]) : zbuf;
                    async_ld16(src, dst + chunk * 4);
                }
            }
        }

        const int ci = cinbase + s;
        const float* tb = &tile[cg][cur][0];
        float r[64];
#pragma unroll
        for (int dz = 0; dz < 4; dz++)
#pragma unroll
        for (int dy = 0; dy < 4; dy++) {
            const int rb = ((2 * pdl + dz) * IH + (2 * phl + dy)) * PITCH +
                           woff + 2 * pwl;
            r[(dz * 4 + dy) * 4 + 0] = tb[rb + 0];
            r[(dz * 4 + dy) * 4 + 1] = tb[rb + 1];
            r[(dz * 4 + dy) * 4 + 2] = tb[rb + 2];
            r[(dz * 4 + dy) * 4 + 3] = tb[rb + 3];
        }

#pragma unroll
        for (int gg = 0; gg < G; gg++) {
            const float4* w4p = (const float4*)&wlds[(ci * G + gg) * 28];
#pragma unroll
            for (int ch = 0; ch < 7; ch++) {
                const float4 wv = w4p[ch];
#pragma unroll
                for (int j = 0; j < 4; j++) {
                    const int tap = ch * 4 + j;
                    if (tap < 27) {
                        const float wvj = (j == 0) ? wv.x : (j == 1) ? wv.y
                                        : (j == 2) ? wv.z : wv.w;
                        const int kd = tap / 9, kh = (tap % 9) / 3, kw = tap % 3;
#pragma unroll
                        for (int od = 0; od < 2; od++)
#pragma unroll
                        for (int oh = 0; oh < 2; oh++)
#pragma unroll
                        for (int ow = 0; ow < 2; ow++)
                            acc[gg][(od * 2 + oh) * 2 + ow] =
                                fmaf(wvj,
                                     r[((od + kd) * 4 + (oh + kh)) * 4 + (ow + kw)],
                                     acc[gg][(od * 2 + oh) * 2 + ow]);
                    }
                }
            }
        }

        if (s + 1 < CPG) {
            __syncthreads();   // drain DMA; all groups' reads of cur done
            cur ^= 1;
        }
    }

    // combine partial accumulators across cin-groups (scratch aliases tile)
    float* af = &acc[0][0];
    if (CSPLIT > 1) {
        __syncthreads();                        // all groups done reading tile
        float* scratch = &tile[0][0][0];
        if (cg > 0) {
#pragma unroll
            for (int idx = 0; idx < G * 8; idx++)
                scratch[(idx * (CSPLIT - 1) + (cg - 1)) * SP + stid] = af[idx];
        }
        __syncthreads();
        if (cg == 0) {
#pragma unroll
            for (int idx = 0; idx < G * 8; idx++) {
                float s = af[idx];
                for (int j = 0; j < CSPLIT - 1; j++)
                    s += scratch[(idx * (CSPLIT - 1) + j) * SP + stid];
                af[idx] = s;
            }
        }
    }

    // epilogue (group 0 only): bias + spline (prefix-Horner) + SiLU + BN + maxpool
    if (cg == 0) {
        const int pdg = pd0 + pdl, phg = ph0 + phl, pwg = pw0 + pwl;
#pragma unroll
        for (int gg = 0; gg < G; gg++) {
            const int c = c0 + gg;
            const float bias = cb[c];
            const float W1 = w1[c], W2 = w2[c];
            const float scale = g[c] * rsqrtf(1.0f + 1e-5f);
            const float bb = beta[c];

            float m = -INFINITY;
#pragma unroll
            for (int i = 0; i < 8; i++) {
                const float y = acc[gg][i] + bias;
                int idx = (int)floorf((y + 1.0f) * 4.5f) + 1;
                idx = min(max(idx, 0), 10);
                const float4 cf = stbl[gg * 11 + idx];
                const float sp = ((cf.x * y - cf.y) * y + cf.z) * y - cf.w;
                const float silu = y / (1.0f + __expf(-y));
                const float o = fmaf(W1 * sp + W2 * silu, scale, bb);
                m = fmaxf(m, o);
            }
            out[((size_t)(n * Cout + c) * PD + pdg) * PH * PW + phg * PW + pwg] = m;
        }
    }
}

// Global average pool: one wave per (n,c)
__global__ __launch_bounds__(64) void mean_kernel(
    const float* __restrict__ h, float* __restrict__ out, int S)
{
    const int nc = blockIdx.x;
    const int lane = threadIdx.x;
    const float* p = h + (size_t)nc * S;
    float s = 0.0f;
    for (int i = lane; i < S; i += 64) s += p[i];
#pragma unroll
    for (int off = 32; off > 0; off >>= 1) s += __shfl_down(s, off, 64);
    if (lane == 0) out[nc] = s / (float)S;
}

// fc1(128->256)+ReLU then fc2(256->2), batch 2
__global__ __launch_bounds__(256) void fc_kernel(
    const float* __restrict__ pooled,
    const float* __restrict__ w1, const float* __restrict__ b1,
    const float* __restrict__ w2, const float* __restrict__ b2,
    float* __restrict__ out)
{
    __shared__ float hbuf[2][256];
    const int j = threadIdx.x;
#pragma unroll
    for (int nn = 0; nn < 2; nn++) {
        float s = b1[j];
        for (int k = 0; k < 128; k++)
            s = fmaf(pooled[nn * 128 + k], w1[j * 128 + k], s);
        hbuf[nn][j] = fmaxf(s, 0.0f);
    }
    __syncthreads();
    const int wid = j >> 6, lane = j & 63;
    const int nn = wid >> 1, oo = wid & 1;
    float s = 0.0f;
    for (int k = lane; k < 256; k += 64) s += hbuf[nn][k] * w2[oo * 256 + k];
#pragma unroll
    for (int off = 32; off > 0; off >>= 1) s += __shfl_down(s, off, 64);
    if (lane == 0) out[nn * 2 + oo] = s + b2[oo];
}

extern "C" void kernel_launch(void* const* d_in, const int* in_sizes, int n_in,
                              void* d_out, int out_size, void* d_ws, size_t ws_size,
                              hipStream_t stream) {
    const float* x      = (const float*)d_in[0];
    const float* c1_w   = (const float*)d_in[1];
    const float* c1_b   = (const float*)d_in[2];
    const float* c1_kn  = (const float*)d_in[3];
    const float* c1_sw  = (const float*)d_in[4];
    const float* c1_w1  = (const float*)d_in[5];
    const float* c1_w2  = (const float*)d_in[6];
    const float* bn1_g  = (const float*)d_in[7];
    const float* bn1_b  = (const float*)d_in[8];
    const float* c2_w   = (const float*)d_in[9];
    const float* c2_b   = (const float*)d_in[10];
    const float* c2_kn  = (const float*)d_in[11];
    const float* c2_sw  = (const float*)d_in[12];
    const float* c2_w1  = (const float*)d_in[13];
    const float* c2_w2  = (const float*)d_in[14];
    const float* bn2_g  = (const float*)d_in[15];
    const float* bn2_b  = (const float*)d_in[16];
    const float* c3_w   = (const float*)d_in[17];
    const float* c3_b   = (const float*)d_in[18];
    const float* c3_kn  = (const float*)d_in[19];
    const float* c3_sw  = (const float*)d_in[20];
    const float* c3_w1  = (const float*)d_in[21];
    const float* c3_w2  = (const float*)d_in[22];
    const float* bn3_g  = (const float*)d_in[23];
    const float* bn3_b  = (const float*)d_in[24];
    const float* fc1_w  = (const float*)d_in[25];
    const float* fc1_b  = (const float*)d_in[26];
    const float* fc2_w  = (const float*)d_in[27];
    const float* fc2_b  = (const float*)d_in[28];

    float* ws = (float*)d_ws;
    float* h1     = ws;                  // 2*32*32^3 = 2,097,152 fl
    float* h2     = h1 + 2097152;        // 2*64*16^3 =   524,288 fl
    float* h3     = h2 + 524288;         // 2*128*8^3 =   131,072 fl
    float* pooled = h3 + 131072;         // 256 fl
    float* zbuf   = pooled + 256;        // 64 B zeros (16B aligned)

    hipMemsetAsync(zbuf, 0, 64, stream);

    // L1: (2,1,64^3)->(2,32,32^3). CSPLIT=1, G=4, tile 4x8x8, ntiles=128.
    // grid = 2*8*128 = 2048 of 256. (unchanged)
    spline_block_kernel<256, 1, 1, 4, 4, 8, 8><<<dim3(2048), dim3(256), 0, stream>>>(
        x, c1_w, c1_b, c1_kn, c1_sw, c1_w1, c1_w2, bn1_g, bn1_b, zbuf, h1,
        2, 32, 64, 64, 64, 128, 16, 4);
    // L2: (2,32,32^3)->(2,64,16^3). CSPLIT=4 x tile 2x4x8 (SP=64) = TPB 256.
    // CPG=8 (chain 32->8). ntiles = 8*4*2 = 64, grid = 2*16*64 = 2048 of 256.
    // LDS ~60 KB -> 2 blocks/CU = 8 waves/CU, 4x DMA streams vs r11.
    spline_block_kernel<256, 32, 4, 4, 2, 4, 8><<<dim3(2048), dim3(256), 0, stream>>>(
        h1, c2_w, c2_b, c2_kn, c2_sw, c2_w1, c2_w2, bn2_g, bn2_b, zbuf, h2,
        2, 64, 32, 32, 32, 64, 8, 2);
    // L3: (2,64,16^3)->(2,128,8^3). CSPLIT=4 x tile 2x4x8 (SP=64) = TPB 256.
    // ntiles = 8, grid = 2*32*8 = 512 of 256. (unchanged from r11)
    spline_block_kernel<256, 64, 4, 4, 2, 4, 8><<<dim3(512), dim3(256), 0, stream>>>(
        h2, c3_w, c3_b, c3_kn, c3_sw, c3_w1, c3_w2, bn3_g, bn3_b, zbuf, h3,
        2, 128, 16, 16, 16, 8, 2, 1);
    // head
    mean_kernel<<<dim3(256), dim3(64), 0, stream>>>(h3, pooled, 512);
    fc_kernel<<<dim3(1), dim3(256), 0, stream>>>(pooled, fc1_w, fc1_b, fc2_w, fc2_b,
                                                 (float*)d_out);
}

// Round 13
// 342.569 us; speedup vs baseline: 1.0884x; 1.0884x over previous
//
#include <hip/hip_runtime.h>
#include <math.h>

// ConvKAN3D: 3x [conv3d(3x3x3,pad1) -> cubic KAN spline + SiLU -> BN(eval) -> maxpool 2x2x2]
// then global mean pool + fc1/relu/fc2.
// r13: LDS-READ-PIPE is the binder (per-CU: 8 waves x 923 LDS-cyc/cin >> VALU).
// Fix: intermediates h1/h2 stored with padded W-pitch (36/20) and +1 column shift
// (pads zeroed by memset) -> staging chunks align exactly (5/row, no waste) and
// window reads become even-based float2 (32 ds_read_b64 vs 64 ds_read_b32).
// L2 reverted to CSPLIT=1 (r12 showed CSPLIT only helps when it adds waves/CU).
// HARD CONSTRAINTS (measured): G<=4 with r[64] (G=8 spills); launch_bounds (TPB,2)
// only (bounds 3 spills); never split cin via global atomics (r5).

#define GLOBAL_AS __attribute__((address_space(1)))
#define LDS_AS    __attribute__((address_space(3)))

static __device__ __forceinline__ void async_ld16(const float* g, float* l) {
    __builtin_amdgcn_global_load_lds((const GLOBAL_AS void*)g, (LDS_AS void*)l,
                                     16, 0, 0);
}

// AL=true: input stored with W-pitch WP and +1 column shift; window start aligned.
template <int TPB_, int CIN, int CSPLIT, int G, int PDT, int PHT, int PWT, bool AL>
__global__ __launch_bounds__(TPB_, 2) void spline_block_kernel(
    const float* __restrict__ x,    // [N, CIN, D, H, WP]
    const float* __restrict__ cw,   // [Cout, CIN, 27]
    const float* __restrict__ cb,
    const float* __restrict__ knots,
    const float* __restrict__ sw,
    const float* __restrict__ w1,
    const float* __restrict__ w2,
    const float* __restrict__ g,
    const float* __restrict__ beta,
    const float* __restrict__ zbuf, // >=64B zeros (16B aligned)
    float* __restrict__ out,        // [N, Cout, PD, PH, OWP] (+OWO col shift)
    int N, int Cout, int D, int H, int W, int WP,
    int OWP, int OWO,
    int ntiles, int nthw, int ntw)
{
    constexpr int SP     = PDT * PHT * PWT;
    constexpr int CPG    = CIN / CSPLIT;
    constexpr int ID     = 2 * PDT + 2;
    constexpr int IH     = 2 * PHT + 2;
    constexpr int CPR    = AL ? 5 : 6;         // chunks (16B) per row
    constexpr int PITCH  = CPR * 4;            // dwords per row in LDS
    constexpr int ROWS   = ID * IH;
    constexpr int CHUNKS = ROWS * CPR;
    constexpr int PHYS   = ROWS * PITCH;
    constexpr int NCH    = (CHUNKS + SP - 1) / SP;
    constexpr int BUFS   = (CPG > 1) ? 2 : 1;
    static_assert(SP * CSPLIT == TPB_, "block = CSPLIT x SP");
    static_assert(CIN % CSPLIT == 0, "cin divisible");
    static_assert(NCH <= 32, "mask fits u32");
    static_assert(!AL || (PWT % 8) == 0, "aligned path needs 16-dword tile step");
    static_assert(CSPLIT == 1 ||
                  (CSPLIT - 1) * SP * G * 8 <= CSPLIT * BUFS * PHYS,
                  "reduction scratch fits in tile");

    __shared__ __align__(16) float tile[CSPLIT][BUFS][PHYS];
    __shared__ float  wlds[CIN * G * 28];
    __shared__ float4 stbl[G * 11];            // spline prefix coeffs {A,3B,3C,D}

    const int PD = D >> 1, PH = H >> 1, PW = W >> 1;
    const int groups = Cout / G;
    const int tid  = threadIdx.x;
    const int cg   = tid / SP;
    const int stid = tid % SP;

    const int bx      = blockIdx.x;
    const int tile_id = bx % ntiles;
    const int t1      = bx / ntiles;
    const int grp     = t1 % groups;
    const int n       = t1 / groups;
    const int c0      = grp * G;
    const int cinbase = cg * CPG;

    const int td  = tile_id / nthw;
    const int rem = tile_id % nthw;
    const int th_ = rem / ntw;
    const int tw_ = rem % ntw;

    // stage weights + spline table (covered by first barrier)
    for (int i = tid; i < CIN * G * 27; i += TPB_) {
        const int t  = i % 27;
        const int cgr = i / 27;
        const int gg = cgr % G;
        const int ci = cgr / G;
        wlds[cgr * 28 + t] = cw[((c0 + gg) * CIN + ci) * 27 + t];
    }
    for (int i = tid; i < G * 11; i += TPB_) {
        const int gg  = i / 11;
        const int cnt = i % 11;
        const int c   = c0 + gg;
        float A = 0.f, B3 = 0.f, C3 = 0.f, Dd = 0.f;
        for (int j = 0; j < cnt; j++) {
            const float s = sw[c * 10 + j];
            const float k = knots[j];
            A  += s;
            B3 += 3.0f * s * k;
            C3 += 3.0f * s * k * k;
            Dd += s * k * k * k;
        }
        stbl[i] = make_float4(A, B3, C3, Dd);
    }

    const int pwl = stid % PWT;
    const int phl = (stid / PWT) % PHT;
    const int pdl = stid / (PWT * PHT);

    const int pd0 = td * PDT, ph0 = th_ * PHT, pw0 = tw_ * PWT;
    const int d0 = 2 * pd0 - 1, h0 = 2 * ph0 - 1;
    const int w0 = 2 * pw0 - 1;
    // staging w-origin in STORED coords: AL -> w0+1 == 2*pw0 (16-dword aligned);
    // else 4-dword-aligned floor of w0 with woff=3 residue.
    const int sorg  = AL ? (2 * pw0) : (w0 & ~3);
    const int woff  = AL ? 0 : (w0 - sorg);

    // per-chunk global offsets + validity (static across cin)
    int off[NCH];
    unsigned vm = 0;
#pragma unroll
    for (int k = 0; k < NCH; k++) {
        const int chunk = stid + SP * k;
        const int row = chunk / CPR, cs = chunk - row * CPR;
        const int dz = row / IH, hy = row - dz * IH;
        const int dd = d0 + dz, hh = h0 + hy;
        const int wsd = sorg + cs * 4;
        bool ok = (chunk < CHUNKS) &
                  ((unsigned)dd < (unsigned)D) &
                  ((unsigned)hh < (unsigned)H);
        if (!AL) ok = ok & ((unsigned)wsd < (unsigned)W);
        off[k] = ok ? (dd * H + hh) * WP + wsd : 0;
        vm |= (unsigned)ok << k;
    }

    const size_t chstride = (size_t)D * H * WP;
    const float* xn = x + (size_t)n * CIN * chstride;

    float acc[G][8];
#pragma unroll
    for (int gg = 0; gg < G; gg++)
#pragma unroll
        for (int i = 0; i < 8; i++) acc[gg][i] = 0.0f;

    __syncthreads();   // weights/table visible before first reads

    // each group stages its first cin into its buf 0
    {
        const float* xc = xn + (size_t)cinbase * chstride;
        float* dst = &tile[cg][0][0];
#pragma unroll
        for (int k = 0; k < NCH; k++) {
            const int chunk = stid + SP * k;
            if ((k + 1) * SP <= CHUNKS || chunk < CHUNKS) {
                const float* src = ((vm >> k) & 1) ? (xc + off[k]) : zbuf;
                async_ld16(src, dst + chunk * 4);
            }
        }
    }
    __syncthreads();

    int cur = 0;
#pragma unroll 1
    for (int s = 0; s < CPG; s++) {
        // prefetch this group's next cin into its other buffer
        if (s + 1 < CPG) {
            const float* xc = xn + (size_t)(cinbase + s + 1) * chstride;
            float* dst = &tile[cg][cur ^ (BUFS - 1)][0];
#pragma unroll
            for (int k = 0; k < NCH; k++) {
                const int chunk = stid + SP * k;
                if ((k + 1) * SP <= CHUNKS || chunk < CHUNKS) {
                    const float* src = ((vm >> k) & 1) ? (xc + off[k]) : zbuf;
                    async_ld16(src, dst + chunk * 4);
                }
            }
        }

        const int ci = cinbase + s;
        const float* tb = &tile[cg][cur][0];
        float r[64];
#pragma unroll
        for (int dz = 0; dz < 4; dz++)
#pragma unroll
        for (int dy = 0; dy < 4; dy++) {
            const int rb = ((2 * pdl + dz) * IH + (2 * phl + dy)) * PITCH +
                           woff + 2 * pwl;
            if (AL) {
                const float2 v0 = *(const float2*)(tb + rb);
                const float2 v1 = *(const float2*)(tb + rb + 2);
                r[(dz * 4 + dy) * 4 + 0] = v0.x;
                r[(dz * 4 + dy) * 4 + 1] = v0.y;
                r[(dz * 4 + dy) * 4 + 2] = v1.x;
                r[(dz * 4 + dy) * 4 + 3] = v1.y;
            } else {
                r[(dz * 4 + dy) * 4 + 0] = tb[rb + 0];
                r[(dz * 4 + dy) * 4 + 1] = tb[rb + 1];
                r[(dz * 4 + dy) * 4 + 2] = tb[rb + 2];
                r[(dz * 4 + dy) * 4 + 3] = tb[rb + 3];
            }
        }

#pragma unroll
        for (int gg = 0; gg < G; gg++) {
            const float4* w4p = (const float4*)&wlds[(ci * G + gg) * 28];
#pragma unroll
            for (int ch = 0; ch < 7; ch++) {
                const float4 wv = w4p[ch];
#pragma unroll
                for (int j = 0; j < 4; j++) {
                    const int tap = ch * 4 + j;
                    if (tap < 27) {
                        const float wvj = (j == 0) ? wv.x : (j == 1) ? wv.y
                                        : (j == 2) ? wv.z : wv.w;
                        const int kd = tap / 9, kh = (tap % 9) / 3, kw = tap % 3;
#pragma unroll
                        for (int od = 0; od < 2; od++)
#pragma unroll
                        for (int oh = 0; oh < 2; oh++)
#pragma unroll
                        for (int ow = 0; ow < 2; ow++)
                            acc[gg][(od * 2 + oh) * 2 + ow] =
                                fmaf(wvj,
                                     r[((od + kd) * 4 + (oh + kh)) * 4 + (ow + kw)],
                                     acc[gg][(od * 2 + oh) * 2 + ow]);
                    }
                }
            }
        }

        if (s + 1 < CPG) {
            __syncthreads();   // drain DMA; all groups' reads of cur done
            cur ^= 1;
        }
    }

    // combine partial accumulators across cin-groups (scratch aliases tile)
    float* af = &acc[0][0];
    if (CSPLIT > 1) {
        __syncthreads();
        float* scratch = &tile[0][0][0];
        if (cg > 0) {
#pragma unroll
            for (int idx = 0; idx < G * 8; idx++)
                scratch[(idx * (CSPLIT - 1) + (cg - 1)) * SP + stid] = af[idx];
        }
        __syncthreads();
        if (cg == 0) {
#pragma unroll
            for (int idx = 0; idx < G * 8; idx++) {
                float s = af[idx];
                for (int j = 0; j < CSPLIT - 1; j++)
                    s += scratch[(idx * (CSPLIT - 1) + j) * SP + stid];
                af[idx] = s;
            }
        }
    }

    // epilogue (group 0 only): bias + spline (prefix-Horner) + SiLU + BN + maxpool
    if (cg == 0) {
        const int pdg = pd0 + pdl, phg = ph0 + phl, pwg = pw0 + pwl;
#pragma unroll
        for (int gg = 0; gg < G; gg++) {
            const int c = c0 + gg;
            const float bias = cb[c];
            const float W1 = w1[c], W2 = w2[c];
            const float scale = g[c] * rsqrtf(1.0f + 1e-5f);
            const float bb = beta[c];

            float m = -INFINITY;
#pragma unroll
            for (int i = 0; i < 8; i++) {
                const float y = acc[gg][i] + bias;
                int idx = (int)floorf((y + 1.0f) * 4.5f) + 1;
                idx = min(max(idx, 0), 10);
                const float4 cf = stbl[gg * 11 + idx];
                const float sp = ((cf.x * y - cf.y) * y + cf.z) * y - cf.w;
                const float silu = y / (1.0f + __expf(-y));
                const float o = fmaf(W1 * sp + W2 * silu, scale, bb);
                m = fmaxf(m, o);
            }
            out[(((size_t)(n * Cout + c) * PD + pdg) * PH + phg) * OWP + OWO + pwg]
                = m;
        }
    }
}

// Global average pool: one wave per (n,c)
__global__ __launch_bounds__(64) void mean_kernel(
    const float* __restrict__ h, float* __restrict__ out, int S)
{
    const int nc = blockIdx.x;
    const int lane = threadIdx.x;
    const float* p = h + (size_t)nc * S;
    float s = 0.0f;
    for (int i = lane; i < S; i += 64) s += p[i];
#pragma unroll
    for (int off = 32; off > 0; off >>= 1) s += __shfl_down(s, off, 64);
    if (lane == 0) out[nc] = s / (float)S;
}

// fc1(128->256)+ReLU then fc2(256->2), batch 2
__global__ __launch_bounds__(256) void fc_kernel(
    const float* __restrict__ pooled,
    const float* __restrict__ w1, const float* __restrict__ b1,
    const float* __restrict__ w2, const float* __restrict__ b2,
    float* __restrict__ out)
{
    __shared__ float hbuf[2][256];
    const int j = threadIdx.x;
#pragma unroll
    for (int nn = 0; nn < 2; nn++) {
        float s = b1[j];
        for (int k = 0; k < 128; k++)
            s = fmaf(pooled[nn * 128 + k], w1[j * 128 + k], s);
        hbuf[nn][j] = fmaxf(s, 0.0f);
    }
    __syncthreads();
    const int wid = j >> 6, lane = j & 63;
    const int nn = wid >> 1, oo = wid & 1;
    float s = 0.0f;
    for (int k = lane; k < 256; k += 64) s += hbuf[nn][k] * w2[oo * 256 + k];
#pragma unroll
    for (int off = 32; off > 0; off >>= 1) s += __shfl_down(s, off, 64);
    if (lane == 0) out[nn * 2 + oo] = s + b2[oo];
}

extern "C" void kernel_launch(void* const* d_in, const int* in_sizes, int n_in,
                              void* d_out, int out_size, void* d_ws, size_t ws_size,
                              hipStream_t stream) {
    const float* x      = (const float*)d_in[0];
    const float* c1_w   = (const float*)d_in[1];
    const float* c1_b   = (const float*)d_in[2];
    const float* c1_kn  = (const float*)d_in[3];
    const float* c1_sw  = (const float*)d_in[4];
    const float* c1_w1  = (const float*)d_in[5];
    const float* c1_w2  = (const float*)d_in[6];
    const float* bn1_g  = (const float*)d_in[7];
    const float* bn1_b  = (const float*)d_in[8];
    const float* c2_w   = (const float*)d_in[9];
    const float* c2_b   = (const float*)d_in[10];
    const float* c2_kn  = (const float*)d_in[11];
    const float* c2_sw  = (const float*)d_in[12];
    const float* c2_w1  = (const float*)d_in[13];
    const float* c2_w2  = (const float*)d_in[14];
    const float* bn2_g  = (const float*)d_in[15];
    const float* bn2_b  = (const float*)d_in[16];
    const float* c3_w   = (const float*)d_in[17];
    const float* c3_b   = (const float*)d_in[18];
    const float* c3_kn  = (const float*)d_in[19];
    const float* c3_sw  = (const float*)d_in[20];
    const float* c3_w1  = (const float*)d_in[21];
    const float* c3_w2  = (const float*)d_in[22];
    const float* bn3_g  = (const float*)d_in[23];
    const float* bn3_b  = (const float*)d_in[24];
    const float* fc1_w  = (const float*)d_in[25];
    const float* fc1_b  = (const float*)d_in[26];
    const float* fc2_w  = (const float*)d_in[27];
    const float* fc2_b  = (const float*)d_in[28];

    // padded intermediate layouts:
    // h1: [2,32,32,32,36], data cols [1..33), pads zero  -> 2,359,296 fl
    // h2: [2,64,16,16,20], data cols [1..17), pads zero  ->   655,360 fl
    // h3: [2,128,8,8,8] unpadded                          ->   131,072 fl
    float* ws = (float*)d_ws;
    float* h1     = ws;
    float* h2     = h1 + 2359296;
    float* h3     = h2 + 655360;
    float* pooled = h3 + 131072;         // 256 fl
    float* zbuf   = pooled + 256;        // 64 B zeros

    hipMemsetAsync(zbuf, 0, 64, stream);
    hipMemsetAsync(h1, 0, 2359296 * sizeof(float), stream);  // zero incl. pads
    hipMemsetAsync(h2, 0, 655360 * sizeof(float), stream);

    // L1: (2,1,64^3)->h1 padded. AL=false (x unpadded), CSPLIT=1, G=4, tile 4x8x8,
    // ntiles=128. grid = 2*8*128 = 2048 of 256.
    spline_block_kernel<256, 1, 1, 4, 4, 8, 8, false>
        <<<dim3(2048), dim3(256), 0, stream>>>(
        x, c1_w, c1_b, c1_kn, c1_sw, c1_w1, c1_w2, bn1_g, bn1_b, zbuf, h1,
        2, 32, 64, 64, 64, 64, 36, 1, 128, 16, 4);
    // L2: h1->h2 padded. AL=true (WP=36), CSPLIT=1, G=4, tile 4x8x8, ntiles=16.
    // grid = 2*16*16 = 512 of 256. LDS ~44 KB. Aligned staging: 5 chunks/row,
    // window reads even-based float2.
    spline_block_kernel<256, 32, 1, 4, 4, 8, 8, true>
        <<<dim3(512), dim3(256), 0, stream>>>(
        h1, c2_w, c2_b, c2_kn, c2_sw, c2_w1, c2_w2, bn2_g, bn2_b, zbuf, h2,
        2, 64, 32, 32, 32, 36, 20, 1, 16, 4, 2);
    // L3: h2->h3. AL=true (WP=20), CSPLIT=4 x tile 2x4x8 (SP=64), ntiles=8.
    // grid = 2*32*8 = 512 of 256. LDS ~68 KB -> 2 blocks/CU, 8 waves/CU.
    spline_block_kernel<256, 64, 4, 4, 2, 4, 8, true>
        <<<dim3(512), dim3(256), 0, stream>>>(
        h2, c3_w, c3_b, c3_kn, c3_sw, c3_w1, c3_w2, bn3_g, bn3_b, zbuf, h3,
        2, 128, 16, 16, 16, 20, 8, 0, 8, 2, 1);
    // head
    mean_kernel<<<dim3(256), dim3(64), 0, stream>>>(h3, pooled, 512);
    fc_kernel<<<dim3(1), dim3(256), 0, stream>>>(pooled, fc1_w, fc1_b, fc2_w, fc2_b,
                                                 (float*)d_out);
}